// Round 14
// baseline (179.468 us; speedup 1.0000x reference)
//
#include <hip/hip_runtime.h>

// BaggingMaxPool: out[d] = mean_k( max_{r in indices[k,:]} inp[r][d] )
// N=1024 rows, D=100000 cols, K=20 rounds, SELECT_N=256.
//
// Round-14: round-13's async ping-pong (gload_lds staging, ONE barrier+
// vmcnt(0)/tile) at CPB=8 so LDS/block = 2x32KB tile + 10.25KB idx +
// 0.63KB wpart = ~74.6KB -> TWO blocks/CU (round 13's 1 block/CU left the
// per-tile drain+barrier uncovered; with 2 blocks, block B computes while
// block A drains). 10 waves/block x 2 = 5 waves/SIMD.
// Per-round lane layout: g=lane>>1 (entry group, 8 entries), u=lane&1
// (4-col unit): 1 sidx b128 + 8 tile b128 per round; reduce = DPP row_shr
// 2/4/8 (VALU pipe) + shfl_xor 16/32 (DS pipe); result in lanes 14/15.
// __launch_bounds__(640,5): 5 waves/EU -> 2 blocks/CU, VGPR cap ~96.

#define N_ROWS   1024
#define D_COLS   100000
#define K_ROUNDS 20
#define SEL_N    256
#define NIDX     (K_ROUNDS * SEL_N)         // 5120
#define CPB      8                          // cols per tile
#define NT       (D_COLS / CPB)             // 12500 tiles (exact)
#define BLOCK    640                        // 10 waves
#define GRID     512
#define WAVES    10
#define RNDS_PW  (K_ROUNDS / WAVES)         // 2
#define NEG_INF  (-3.402823466e+38f)

// acc = max(acc, lane_shifted_down_by_N within 16-lane row); bound lanes no-op.
template<int CTRL>
__device__ __forceinline__ float dpp_shr_max(float x) {
    const int xi = __float_as_int(x);
    const int sh = __builtin_amdgcn_update_dpp(xi, xi, CTRL, 0xF, 0xF, false);
    return fmaxf(x, __int_as_float(sh));
}
#define ROW_SHR2 0x112
#define ROW_SHR4 0x114
#define ROW_SHR8 0x118

__device__ __forceinline__ void async_cp16(const float* g, float* l) {
    __builtin_amdgcn_global_load_lds(
        (const __attribute__((address_space(1))) unsigned int*)g,
        (__attribute__((address_space(3))) unsigned int*)l,
        16, 0, 0);
}

// Waves 0..7 stage 128 rows each (4 x gload_lds of 32 rows x 8 cols).
// Lane l -> row +(l>>1), col-unit (l&1): LDS offset l*16B matches
// ((l>>1)*8 + (l&1)*4) floats. Dest wave-uniform, source per-lane.
__device__ __forceinline__ void stage_tile(const float* __restrict__ inp,
                                           float* __restrict__ buf,
                                           int colbase, int wave, int lane) {
    if (wave < 8) {
        const int rsub = lane >> 1;             // 0..31
        const int c4   = (lane & 1) * 4;        // 0,4
        #pragma unroll
        for (int it = 0; it < 4; ++it) {
            const int row = wave * 128 + it * 32 + rsub;
            const float* g = inp + (size_t)row * D_COLS + colbase + c4;   // per-lane
            float* l = &buf[(wave * 128 + it * 32) * CPB];                // uniform
            async_cp16(g, l);
        }
    }
}

__global__ __launch_bounds__(BLOCK, 5) void bagmax_kernel(
    const float* __restrict__ inp,
    const int*   __restrict__ indices,
    float*       __restrict__ out)
{
    __shared__ float tile[2][N_ROWS * CPB];                 // 64 KB
    __shared__ __align__(16) unsigned short sidx[NIDX];     // 10.25 KB
    __shared__ float wpart[2][WAVES][CPB];                  // 640 B

    const int tid  = threadIdx.x;
    const int lane = tid & 63;
    const int wave = tid >> 6;                               // 0..9

    // XCD-chunk swizzle: each XCD's 64 block-slots are consecutive chunks.
    const int b   = blockIdx.x;
    const int swz = (b & 7) * 64 + (b >> 3);                // bijective on [0,512)
    const int cnt = (NT - swz + GRID - 1) / GRID;           // 24 or 25 tiles

    // ---- idx preload: coalesced, u16 transposed to [k][g:5][j:3] ----
    for (int i = tid; i < NIDX; i += BLOCK) {
        const int p   = i & 255;
        const int dst = (i & ~255) | ((p & 31) << 3) | (p >> 5);
        sidx[dst] = (unsigned short)indices[i];
    }

    // ---- prologue: stage tile 0 ----
    stage_tile(inp, &tile[0][0], swz * CPB, wave, lane);
    asm volatile("s_waitcnt vmcnt(0)" ::: "memory");
    __syncthreads();

    const int g = lane >> 1;            // entry group 0..31
    const int u = lane & 1;             // col unit (cols u*4..u*4+3)

    #pragma unroll 1
    for (int i = 0; i < cnt; ++i) {
        const int cur = i & 1;

        // ---- issue async staging of tile i+1 into the other buffer ----
        if (i + 1 < cnt)
            stage_tile(inp, &tile[cur ^ 1][0], (swz + (i + 1) * GRID) * CPB, wave, lane);

        // ---- finalize tile i-1 (other parity wpart, stable since barrier) ----
        if (i > 0 && tid < CPB) {
            float s = 0.f;
            #pragma unroll
            for (int w = 0; w < WAVES; ++w) s += wpart[cur ^ 1][w][tid];
            out[(swz + (i - 1) * GRID) * CPB + tid] = s * (1.0f / (float)K_ROUNDS);
        }

        // ---- round-major compute on buf[cur]: wave owns rounds 2w,2w+1 ----
        const float* tb = &tile[cur][0];
        float4 rsum = make_float4(0.f, 0.f, 0.f, 0.f);
        #pragma unroll
        for (int kk = 0; kk < RNDS_PW; ++kk) {
            const int k = wave * RNDS_PW + kk;

            // 8 entries for this (round, group): one b128 of u16x8
            const uint4 w0 = *reinterpret_cast<const uint4*>(&sidx[k * SEL_N + g * 8]);
            unsigned int e[8];
            e[0] = w0.x & 0xFFFFu; e[1] = w0.x >> 16;
            e[2] = w0.y & 0xFFFFu; e[3] = w0.y >> 16;
            e[4] = w0.z & 0xFFFFu; e[5] = w0.z >> 16;
            e[6] = w0.w & 0xFFFFu; e[7] = w0.w >> 16;

            float4 a0 = make_float4(NEG_INF, NEG_INF, NEG_INF, NEG_INF);
            float4 a1 = a0;
            #pragma unroll
            for (int j = 0; j < 8; j += 2) {
                const float4 v0 = *reinterpret_cast<const float4*>(&tb[e[j]     * CPB + u * 4]);
                const float4 v1 = *reinterpret_cast<const float4*>(&tb[e[j + 1] * CPB + u * 4]);
                a0.x = fmaxf(a0.x, v0.x); a0.y = fmaxf(a0.y, v0.y);
                a0.z = fmaxf(a0.z, v0.z); a0.w = fmaxf(a0.w, v0.w);
                a1.x = fmaxf(a1.x, v1.x); a1.y = fmaxf(a1.y, v1.y);
                a1.z = fmaxf(a1.z, v1.z); a1.w = fmaxf(a1.w, v1.w);
            }
            float4 acc;
            acc.x = fmaxf(a0.x, a1.x); acc.y = fmaxf(a0.y, a1.y);
            acc.z = fmaxf(a0.z, a1.z); acc.w = fmaxf(a0.w, a1.w);

            // strides 2,4,8: DPP funnel (VALU) -> lanes 14/15 of each row
            acc.x = dpp_shr_max<ROW_SHR2>(acc.x); acc.y = dpp_shr_max<ROW_SHR2>(acc.y);
            acc.z = dpp_shr_max<ROW_SHR2>(acc.z); acc.w = dpp_shr_max<ROW_SHR2>(acc.w);
            acc.x = dpp_shr_max<ROW_SHR4>(acc.x); acc.y = dpp_shr_max<ROW_SHR4>(acc.y);
            acc.z = dpp_shr_max<ROW_SHR4>(acc.z); acc.w = dpp_shr_max<ROW_SHR4>(acc.w);
            acc.x = dpp_shr_max<ROW_SHR8>(acc.x); acc.y = dpp_shr_max<ROW_SHR8>(acc.y);
            acc.z = dpp_shr_max<ROW_SHR8>(acc.z); acc.w = dpp_shr_max<ROW_SHR8>(acc.w);
            // strides 16,32: cross-row (DS pipe)
            acc.x = fmaxf(acc.x, __shfl_xor(acc.x, 16, 64));
            acc.y = fmaxf(acc.y, __shfl_xor(acc.y, 16, 64));
            acc.z = fmaxf(acc.z, __shfl_xor(acc.z, 16, 64));
            acc.w = fmaxf(acc.w, __shfl_xor(acc.w, 16, 64));
            acc.x = fmaxf(acc.x, __shfl_xor(acc.x, 32, 64));
            acc.y = fmaxf(acc.y, __shfl_xor(acc.y, 32, 64));
            acc.z = fmaxf(acc.z, __shfl_xor(acc.z, 32, 64));
            acc.w = fmaxf(acc.w, __shfl_xor(acc.w, 32, 64));

            rsum.x += acc.x; rsum.y += acc.y; rsum.z += acc.z; rsum.w += acc.w;
        }
        if (lane == 14 || lane == 15)   // full reduction lives here; u = lane&1
            *reinterpret_cast<float4*>(&wpart[cur][wave][u * 4]) = rsum;

        // ---- drain prefetch + one barrier per tile ----
        asm volatile("s_waitcnt vmcnt(0)" ::: "memory");
        __syncthreads();
    }

    // ---- epilogue: finalize the last tile ----
    if (tid < CPB) {
        const int pb = (cnt - 1) & 1;
        float s = 0.f;
        #pragma unroll
        for (int w = 0; w < WAVES; ++w) s += wpart[pb][w][tid];
        out[(swz + (cnt - 1) * GRID) * CPB + tid] = s * (1.0f / (float)K_ROUNDS);
    }
}

extern "C" void kernel_launch(void* const* d_in, const int* in_sizes, int n_in,
                              void* d_out, int out_size, void* d_ws, size_t ws_size,
                              hipStream_t stream) {
    const float* inp     = (const float*)d_in[0];
    const int*   indices = (const int*)d_in[1];
    float*       out     = (float*)d_out;

    bagmax_kernel<<<GRID, BLOCK, 0, stream>>>(inp, indices, out);
}

// Round 15
// 117.651 us; speedup vs baseline: 1.5254x; 1.5254x over previous
//
#include <hip/hip_runtime.h>

// BaggingMaxPool: out[d] = mean_k( max_{r in indices[k,:]} inp[r][d] )
// N=1024 rows, D=100000 cols, K=20 rounds, SELECT_N=256.
//
// Round-15 = round-13 (best, 115.6us) + ONE change: bank-conflict swizzle
// on the LDS tile. Round-13's reads: row r = 64B -> banks 0-15/16-31 by
// parity; fixed col-unit u always hits banks u*4..u*4+3 (+-16) -> 4-8-way
// conflict on all 360 ds_read_b128/tile (9.2M SQ_LDS_BANK_CONFLICT).
// Swizzle: physical slot s of row r holds logical unit u = s ^ sw(r),
// sw(r)=(r>>1)&3 -> fixed-u lanes spread over 8 bank-quads (~2-way, free).
// gload_lds dest stays LINEAR (HW requirement); the global SOURCE col is
// pre-swizzled (rule #21). sw reduces to a per-lane constant in staging:
// c4 = ((lane&3) ^ ((lane>>3)&3))*4. Consumer: E = e*16 + sw(e)*4 at
// unpack; address = E ^ (u<<2) (bit-disjoint XOR trick), +2 VALU/entry.

#define N_ROWS   1024
#define D_COLS   100000
#define K_ROUNDS 20
#define SEL_N    256
#define NIDX     (K_ROUNDS * SEL_N)         // 5120
#define CPB      16                         // cols per tile
#define NT       (D_COLS / CPB)             // 6250 tiles (exact)
#define BLOCK    640                        // 10 waves
#define GRID     256
#define WAVES    10
#define RNDS_PW  (K_ROUNDS / WAVES)         // 2
#define NEG_INF  (-3.402823466e+38f)

// acc = max(acc, lane_shifted_down_by_N) within each 16-lane row.
template<int CTRL>
__device__ __forceinline__ float dpp_shr_max(float x) {
    const int xi = __float_as_int(x);
    const int sh = __builtin_amdgcn_update_dpp(xi, xi, CTRL, 0xF, 0xF, false);
    return fmaxf(x, __int_as_float(sh));
}
#define ROW_SHR4 0x114
#define ROW_SHR8 0x118

__device__ __forceinline__ void async_cp16(const float* g, float* l) {
    __builtin_amdgcn_global_load_lds(
        (const __attribute__((address_space(1))) unsigned int*)g,
        (__attribute__((address_space(3))) unsigned int*)l,
        16, 0, 0);
}

// Waves 0..7 each stage 128 rows (8 x gload_lds of 16 rows x 16 cols).
// LDS dest wave-uniform (linear); HW adds lane*16B: lane l -> row +(l>>2),
// slot l&3. Global source col unit = (l&3) ^ sw(row); since row mod 8 ==
// (l>>2) mod 8 in every instr, sw = (l>>3)&3 -> per-lane constant.
__device__ __forceinline__ void stage_tile(const float* __restrict__ inp,
                                           float* __restrict__ buf,
                                           int colbase, int wave, int lane) {
    if (wave < 8) {
        const int rsub = lane >> 2;                          // 0..15
        const int c4   = (((lane & 3) ^ ((lane >> 3) & 3))) * 4;  // swizzled src unit
        #pragma unroll
        for (int it = 0; it < 8; ++it) {
            const int row = wave * 128 + it * 16 + rsub;
            const float* g = inp + (size_t)row * D_COLS + colbase + c4;   // per-lane
            float* l = &buf[(wave * 128 + it * 16) * CPB];                // uniform
            async_cp16(g, l);
        }
    }
}

__global__ __launch_bounds__(BLOCK, 1) void bagmax_kernel(
    const float* __restrict__ inp,
    const int*   __restrict__ indices,
    float*       __restrict__ out)
{
    __shared__ float tile[2][N_ROWS * CPB];                 // 128 KB
    __shared__ __align__(16) unsigned short sidx[NIDX];     // 10.25 KB
    __shared__ float wpart[2][WAVES][CPB];                  // 1.25 KB

    const int tid  = threadIdx.x;
    const int lane = tid & 63;
    const int wave = tid >> 6;                               // 0..9

    // XCD-chunk swizzle: each XCD's 32 CUs own 32 consecutive col-chunks.
    const int b   = blockIdx.x;
    const int swz = (b & 7) * 32 + (b >> 3);
    const int cnt = (NT - swz + GRID - 1) / GRID;           // 24 or 25 tiles

    // ---- idx preload: coalesced, u16 transposed to [k][g][j] ----
    for (int i = tid; i < NIDX; i += BLOCK) {
        const int p   = i & 255;
        const int dst = (i & ~255) | ((p & 15) << 4) | (p >> 4);
        sidx[dst] = (unsigned short)indices[i];
    }

    // ---- prologue: issue stage of tile 0 ----
    stage_tile(inp, &tile[0][0], swz * CPB, wave, lane);
    asm volatile("s_waitcnt vmcnt(0)" ::: "memory");
    __syncthreads();

    const int g  = lane >> 2;           // entry group 0..15
    const int u4 = (lane & 3) << 2;     // col-unit word offset (0,4,8,12)

    #pragma unroll 1
    for (int i = 0; i < cnt; ++i) {
        const int cur = i & 1;

        // ---- issue async staging of tile i+1 into the other buffer ----
        if (i + 1 < cnt)
            stage_tile(inp, &tile[cur ^ 1][0], (swz + (i + 1) * GRID) * CPB, wave, lane);

        // ---- finalize tile i-1 (other parity wpart, stable since barrier) ----
        if (i > 0 && tid < CPB) {
            float s = 0.f;
            #pragma unroll
            for (int w = 0; w < WAVES; ++w) s += wpart[cur ^ 1][w][tid];
            out[(swz + (i - 1) * GRID) * CPB + tid] = s * (1.0f / (float)K_ROUNDS);
        }

        // ---- round-major compute on buf[cur]: wave owns rounds 2w,2w+1 ----
        const float* tb = &tile[cur][0];
        float4 rsum = make_float4(0.f, 0.f, 0.f, 0.f);
        #pragma unroll
        for (int kk = 0; kk < RNDS_PW; ++kk) {
            const int k = wave * RNDS_PW + kk;

            const uint4* sp = reinterpret_cast<const uint4*>(&sidx[k * SEL_N + g * 16]);
            const uint4 w0 = sp[0];
            const uint4 w1 = sp[1];
            // E = e*16 + ((e>>1)&3)*4  (swizzled base word-offset of row e)
            unsigned int E[16];
            {
                unsigned int e;
                e = w0.x & 0xFFFFu; E[0]  = (e << 4) | (((e >> 1) & 3u) << 2);
                e = w0.x >> 16;     E[1]  = (e << 4) | (((e >> 1) & 3u) << 2);
                e = w0.y & 0xFFFFu; E[2]  = (e << 4) | (((e >> 1) & 3u) << 2);
                e = w0.y >> 16;     E[3]  = (e << 4) | (((e >> 1) & 3u) << 2);
                e = w0.z & 0xFFFFu; E[4]  = (e << 4) | (((e >> 1) & 3u) << 2);
                e = w0.z >> 16;     E[5]  = (e << 4) | (((e >> 1) & 3u) << 2);
                e = w0.w & 0xFFFFu; E[6]  = (e << 4) | (((e >> 1) & 3u) << 2);
                e = w0.w >> 16;     E[7]  = (e << 4) | (((e >> 1) & 3u) << 2);
                e = w1.x & 0xFFFFu; E[8]  = (e << 4) | (((e >> 1) & 3u) << 2);
                e = w1.x >> 16;     E[9]  = (e << 4) | (((e >> 1) & 3u) << 2);
                e = w1.y & 0xFFFFu; E[10] = (e << 4) | (((e >> 1) & 3u) << 2);
                e = w1.y >> 16;     E[11] = (e << 4) | (((e >> 1) & 3u) << 2);
                e = w1.z & 0xFFFFu; E[12] = (e << 4) | (((e >> 1) & 3u) << 2);
                e = w1.z >> 16;     E[13] = (e << 4) | (((e >> 1) & 3u) << 2);
                e = w1.w & 0xFFFFu; E[14] = (e << 4) | (((e >> 1) & 3u) << 2);
                e = w1.w >> 16;     E[15] = (e << 4) | (((e >> 1) & 3u) << 2);
            }

            float4 a0 = make_float4(NEG_INF, NEG_INF, NEG_INF, NEG_INF);
            float4 a1 = a0;
            #pragma unroll
            for (int j = 0; j < 16; j += 2) {
                const float4 v0 = *reinterpret_cast<const float4*>(&tb[E[j]     ^ u4]);
                const float4 v1 = *reinterpret_cast<const float4*>(&tb[E[j + 1] ^ u4]);
                a0.x = fmaxf(a0.x, v0.x); a0.y = fmaxf(a0.y, v0.y);
                a0.z = fmaxf(a0.z, v0.z); a0.w = fmaxf(a0.w, v0.w);
                a1.x = fmaxf(a1.x, v1.x); a1.y = fmaxf(a1.y, v1.y);
                a1.z = fmaxf(a1.z, v1.z); a1.w = fmaxf(a1.w, v1.w);
            }
            float4 acc;
            acc.x = fmaxf(a0.x, a1.x); acc.y = fmaxf(a0.y, a1.y);
            acc.z = fmaxf(a0.z, a1.z); acc.w = fmaxf(a0.w, a1.w);

            // strides 4,8: DPP funnel (VALU pipe) -> valid in lanes 12..15
            acc.x = dpp_shr_max<ROW_SHR4>(acc.x); acc.y = dpp_shr_max<ROW_SHR4>(acc.y);
            acc.z = dpp_shr_max<ROW_SHR4>(acc.z); acc.w = dpp_shr_max<ROW_SHR4>(acc.w);
            acc.x = dpp_shr_max<ROW_SHR8>(acc.x); acc.y = dpp_shr_max<ROW_SHR8>(acc.y);
            acc.z = dpp_shr_max<ROW_SHR8>(acc.z); acc.w = dpp_shr_max<ROW_SHR8>(acc.w);
            // strides 16,32: cross-row (DS pipe)
            acc.x = fmaxf(acc.x, __shfl_xor(acc.x, 16, 64));
            acc.y = fmaxf(acc.y, __shfl_xor(acc.y, 16, 64));
            acc.z = fmaxf(acc.z, __shfl_xor(acc.z, 16, 64));
            acc.w = fmaxf(acc.w, __shfl_xor(acc.w, 16, 64));
            acc.x = fmaxf(acc.x, __shfl_xor(acc.x, 32, 64));
            acc.y = fmaxf(acc.y, __shfl_xor(acc.y, 32, 64));
            acc.z = fmaxf(acc.z, __shfl_xor(acc.z, 32, 64));
            acc.w = fmaxf(acc.w, __shfl_xor(acc.w, 32, 64));

            rsum.x += acc.x; rsum.y += acc.y; rsum.z += acc.z; rsum.w += acc.w;
        }
        if (g == 3)   // lanes 12..15 (and replicas) hold the full reduction
            *reinterpret_cast<float4*>(&wpart[cur][wave][lane & 3 ? (lane & 3) * 4 : 0]) = rsum;

        // ---- drain prefetch + one barrier per tile ----
        asm volatile("s_waitcnt vmcnt(0)" ::: "memory");
        __syncthreads();
    }

    // ---- epilogue: finalize the last tile ----
    if (tid < CPB) {
        const int pb = (cnt - 1) & 1;
        float s = 0.f;
        #pragma unroll
        for (int w = 0; w < WAVES; ++w) s += wpart[pb][w][tid];
        out[(swz + (cnt - 1) * GRID) * CPB + tid] = s * (1.0f / (float)K_ROUNDS);
    }
}

extern "C" void kernel_launch(void* const* d_in, const int* in_sizes, int n_in,
                              void* d_out, int out_size, void* d_ws, size_t ws_size,
                              hipStream_t stream) {
    const float* inp     = (const float*)d_in[0];
    const int*   indices = (const int*)d_in[1];
    float*       out     = (float*)d_out;

    bagmax_kernel<<<GRID, BLOCK, 0, stream>>>(inp, indices, out);
}